// Round 1
// baseline (19325.902 us; speedup 1.0000x reference)
//
#include <hip/hip_runtime.h>
#include <math.h>

#define N_NODES 1000
#define BATCH   32
#define SEQ     48
#define FRAW    21
#define HID     64
#define FEAT    40
#define CATF    104                 // FEAT + HID
#define GATE    128                 // 2*HID
#define NCOLS   (BATCH*CATF)        // 3328
#define HN      (N_NODES*HID)       // 64000 per batch
#define GN      (N_NODES*GATE)      // 128000 per batch

// ---------------- Laplacian ----------------
__global__ void k_rowsum(const float* __restrict__ adj, float* __restrict__ dinv) {
    int m = blockIdx.x;
    float s = 0.f;
    for (int n = threadIdx.x; n < N_NODES; n += blockDim.x)
        s += adj[(size_t)m*N_NODES + n];
    __shared__ float red[256];
    red[threadIdx.x] = s; __syncthreads();
    for (int st = 128; st > 0; st >>= 1) {
        if (threadIdx.x < st) red[threadIdx.x] += red[threadIdx.x + st];
        __syncthreads();
    }
    if (threadIdx.x == 0) dinv[m] = rsqrtf(red[0] + 1.0f);  // +1 self loop
}

__global__ void k_buildL(const float* __restrict__ adj, const float* __restrict__ dinv,
                         float* __restrict__ L) {
    int idx = blockIdx.x * blockDim.x + threadIdx.x;
    if (idx >= N_NODES * N_NODES) return;
    int m = idx / N_NODES, n = idx - m * N_NODES;
    float a = adj[idx] + (m == n ? 1.f : 0.f);
    L[idx] = dinv[m] * a * dinv[n];
}

// ---------------- cat1: x_t projection + h ----------------
// cat[n][b*104 + f]; f<40 aspect proj of inputs[b,t,n,:], f>=40 h[b][n*64+f-40]
__global__ void k_cat1(const float* __restrict__ inputs, int t,
                       const float* __restrict__ Wo, const float* __restrict__ bo,
                       const float* __restrict__ Wd, const float* __restrict__ bd,
                       const float* __restrict__ We, const float* __restrict__ be,
                       const float* __restrict__ Wi, const float* __restrict__ bi,
                       const float* __restrict__ h, float* __restrict__ cat) {
    int p = blockIdx.x;               // b*N + n
    int b = p / N_NODES, n = p - b * N_NODES;
    __shared__ float raw[FRAW];
    const float* inp = inputs + ((size_t)(b * SEQ + t) * N_NODES + n) * FRAW;
    if (threadIdx.x < FRAW) raw[threadIdx.x] = inp[threadIdx.x];
    __syncthreads();
    int f = threadIdx.x;
    if (f >= CATF) return;
    float v;
    if (f < FEAT) {
        int a = f % 10, g = f / 10;
        if (g == 0)
            v = bo[a] + raw[2]*Wo[0*10+a] + raw[5]*Wo[1*10+a] + raw[8]*Wo[2*10+a]
                      + raw[9]*Wo[3*10+a] + raw[12]*Wo[4*10+a];
        else if (g == 1)
            v = bd[a] + raw[10]*Wd[0*10+a] + raw[14]*Wd[1*10+a] + raw[15]*Wd[2*10+a];
        else if (g == 2)
            v = be[a] + raw[13]*We[0*10+a] + raw[17]*We[1*10+a];
        else
            v = bi[a] + raw[19]*Wi[0*10+a] + raw[20]*Wi[1*10+a];
    } else {
        v = h[(size_t)b*HN + n*HID + (f - FEAT)];
    }
    cat[(size_t)n*NCOLS + b*CATF + f] = v;
}

// ---------------- cat2: overwrite h-part with r*h ----------------
__global__ void k_cat2(const float* __restrict__ ru, const float* __restrict__ h,
                       float* __restrict__ cat) {
    int idx = blockIdx.x * blockDim.x + threadIdx.x;   // over B*HN
    if (idx >= BATCH * HN) return;
    int b = idx / HN, i = idx - b * HN;
    int n = i / HID, c = i - n * HID;
    float rh = ru[(size_t)b*GN + i] * h[(size_t)b*HN + i];  // r = flat first half
    cat[(size_t)n*NCOLS + b*CATF + FEAT + c] = rh;
}

// ---------------- big GEMM: C[m][j] = sum_k L[m][k] * B[k][j] ----------------
#define BM 128
#define BN 64
#define BK 16
__global__ __launch_bounds__(256) void k_gemm(const float* __restrict__ A,
                                              const float* __restrict__ Bm,
                                              float* __restrict__ C) {
    __shared__ float As[BK][BM + 4];
    __shared__ float Bs[BK][BN + 4];
    int m0 = blockIdx.y * BM;
    int n0 = blockIdx.x * BN;
    int tid = threadIdx.x;
    int tx = tid & 15, ty = tid >> 4;
    float acc[8][4] = {};
    for (int k0 = 0; k0 < N_NODES; k0 += BK) {
        {   // A tile: 128 rows x 16 k, 2 threads/row, 8 consecutive k each
            int i = tid >> 1;
            int kk = (tid & 1) * 8;
            int m = m0 + i;
            #pragma unroll
            for (int q = 0; q < 8; ++q) {
                int k = k0 + kk + q;
                As[kk + q][i] = (m < N_NODES && k < N_NODES)
                                    ? A[(size_t)m*N_NODES + k] : 0.f;
            }
        }
        {   // B tile: 16 k x 64 cols, float4 per thread
            int k = tid >> 4;
            int j = (tid & 15) * 4;
            int kg = k0 + k;
            if (kg < N_NODES) {
                float4 v = *(const float4*)(Bm + (size_t)kg*NCOLS + n0 + j);
                Bs[k][j] = v.x; Bs[k][j+1] = v.y; Bs[k][j+2] = v.z; Bs[k][j+3] = v.w;
            } else {
                Bs[k][j] = Bs[k][j+1] = Bs[k][j+2] = Bs[k][j+3] = 0.f;
            }
        }
        __syncthreads();
        #pragma unroll
        for (int k = 0; k < BK; ++k) {
            float a[8], bb[4];
            #pragma unroll
            for (int i = 0; i < 8; ++i) a[i] = As[k][ty*8 + i];
            #pragma unroll
            for (int j = 0; j < 4; ++j) bb[j] = Bs[k][tx*4 + j];
            #pragma unroll
            for (int i = 0; i < 8; ++i)
                #pragma unroll
                for (int j = 0; j < 4; ++j)
                    acc[i][j] += a[i] * bb[j];
        }
        __syncthreads();
    }
    #pragma unroll
    for (int i = 0; i < 8; ++i) {
        int m = m0 + ty*8 + i;
        if (m < N_NODES) {
            float* dst = C + (size_t)m*NCOLS + n0 + tx*4;
            #pragma unroll
            for (int j = 0; j < 4; ++j) dst[j] = acc[i][j];
        }
    }
}

// ---------------- gate: ru = sigmoid(ag @ W1 + b1) ----------------
__global__ void k_gate(const float* __restrict__ ag, const float* __restrict__ W1,
                       const float* __restrict__ b1, float* __restrict__ ru) {
    int p = blockIdx.x;               // b*N + m
    int b = p / N_NODES, m = p - b * N_NODES;
    __shared__ float row[CATF];
    if (threadIdx.x < CATF)
        row[threadIdx.x] = ag[(size_t)m*NCOLS + b*CATF + threadIdx.x];
    __syncthreads();
    int k = threadIdx.x;              // 0..127
    float acc = b1[k];
    #pragma unroll 8
    for (int f = 0; f < CATF; ++f) acc += row[f] * W1[f*GATE + k];
    ru[(size_t)b*GN + m*GATE + k] = 1.f / (1.f + expf(-acc));
}

// ---------------- update: c = tanh(ag2 @ W2 + b2); h' = u h + (1-u) c ----------------
__global__ void k_update(const float* __restrict__ ag, const float* __restrict__ W2,
                         const float* __restrict__ b2, const float* __restrict__ ru,
                         const float* __restrict__ h, float* __restrict__ hn) {
    int p = blockIdx.x;               // b*N + m
    int b = p / N_NODES, m = p - b * N_NODES;
    __shared__ float row[CATF];
    if (threadIdx.x < CATF)
        row[threadIdx.x] = ag[(size_t)m*NCOLS + b*CATF + threadIdx.x];
    __syncthreads();
    int c = threadIdx.x;
    if (c >= HID) return;
    float acc = b2[c];
    #pragma unroll 8
    for (int f = 0; f < CATF; ++f) acc += row[f] * W2[f*HID + c];
    float cv = tanhf(acc);
    size_t i = (size_t)b*HN + m*HID + c;
    float u = ru[(size_t)b*GN + HN + m*HID + c];   // u = flat second half
    hn[i] = u * h[i] + (1.f - u) * cv;
}

// ---------------- workspace layout (float offsets) ----------------
#define OFF_L    0
#define OFF_DINV 1000192
#define OFF_CAT  1001216
#define OFF_AG   4329216
#define OFF_RU   7657216
#define OFF_H0   11753216
#define OFF_H1   13801216
// total floats: 15849216  -> ~63.4 MB

extern "C" void kernel_launch(void* const* d_in, const int* in_sizes, int n_in,
                              void* d_out, int out_size, void* d_ws, size_t ws_size,
                              hipStream_t stream) {
    const float* inputs = (const float*)d_in[0];
    const float* adj    = (const float*)d_in[1];
    const float* Wo = (const float*)d_in[2];  const float* bo = (const float*)d_in[3];
    const float* Wd = (const float*)d_in[4];  const float* bd = (const float*)d_in[5];
    const float* We = (const float*)d_in[6];  const float* be = (const float*)d_in[7];
    const float* Wi = (const float*)d_in[8];  const float* bi = (const float*)d_in[9];
    const float* W1 = (const float*)d_in[10]; const float* b1 = (const float*)d_in[11];
    const float* W2 = (const float*)d_in[12]; const float* b2 = (const float*)d_in[13];
    float* out = (float*)d_out;

    float* ws   = (float*)d_ws;
    float* L    = ws + OFF_L;
    float* dinv = ws + OFF_DINV;
    float* cat  = ws + OFF_CAT;
    float* ag   = ws + OFF_AG;
    float* ru   = ws + OFF_RU;
    float* h0   = ws + OFF_H0;
    float* h1   = ws + OFF_H1;

    // Laplacian
    k_rowsum<<<N_NODES, 256, 0, stream>>>(adj, dinv);
    k_buildL<<<(N_NODES*N_NODES + 255)/256, 256, 0, stream>>>(adj, dinv, L);

    // h0 = 0
    hipMemsetAsync(h0, 0, (size_t)BATCH*HN*sizeof(float), stream);

    dim3 gemm_grid(NCOLS / BN, (N_NODES + BM - 1) / BM);

    for (int t = 0; t < SEQ; ++t) {
        const float* hcur = (t & 1) ? h1 : h0;
        float* hnext = (t == SEQ - 1) ? out : ((t & 1) ? h0 : h1);

        k_cat1<<<BATCH*N_NODES, 128, 0, stream>>>(inputs, t, Wo, bo, Wd, bd,
                                                  We, be, Wi, bi, hcur, cat);
        k_gemm<<<gemm_grid, 256, 0, stream>>>(L, cat, ag);
        k_gate<<<BATCH*N_NODES, GATE, 0, stream>>>(ag, W1, b1, ru);
        k_cat2<<<(BATCH*HN + 255)/256, 256, 0, stream>>>(ru, hcur, cat);
        k_gemm<<<gemm_grid, 256, 0, stream>>>(L, cat, ag);
        k_update<<<BATCH*N_NODES, 128, 0, stream>>>(ag, W2, b2, ru, hcur, hnext);
    }
}

// Round 2
// 11448.507 us; speedup vs baseline: 1.6881x; 1.6881x over previous
//
#include <hip/hip_runtime.h>
#include <math.h>

#define NN    1000
#define KP    1024
#define BATCH 32
#define SEQ   48
#define HID   64
#define FEAT  40
#define GATEW 128
#define XCOLS (BATCH*FEAT)   // 1280
#define HCOLS (BATCH*HID)    // 2048

typedef __attribute__((ext_vector_type(8))) short  short8v;
typedef __attribute__((ext_vector_type(8))) unsigned short ushort8v;
typedef __attribute__((ext_vector_type(4))) float  float4v;

__device__ __forceinline__ unsigned short f2bf(float x) {
    union { float f; unsigned u; } v; v.f = x;
    unsigned r = v.u + 0x7FFF + ((v.u >> 16) & 1);
    return (unsigned short)(r >> 16);
}
__device__ __forceinline__ float bf2f(unsigned short h) {
    union { unsigned u; float f; } v; v.u = ((unsigned)h) << 16;
    return v.f;
}

// ---------------- Laplacian ----------------
__global__ void k_rowsum(const float* __restrict__ adj, float* __restrict__ dinv) {
    int m = blockIdx.x;
    float s = 0.f;
    for (int n = threadIdx.x; n < NN; n += blockDim.x)
        s += adj[(size_t)m*NN + n];
    __shared__ float red[256];
    red[threadIdx.x] = s; __syncthreads();
    for (int st = 128; st > 0; st >>= 1) {
        if (threadIdx.x < st) red[threadIdx.x] += red[threadIdx.x + st];
        __syncthreads();
    }
    if (threadIdx.x == 0) dinv[m] = rsqrtf(red[0] + 1.0f);
}

__global__ void k_buildL(const float* __restrict__ adj, const float* __restrict__ dinv,
                         unsigned short* __restrict__ Lhi, unsigned short* __restrict__ Llo) {
    int idx = blockIdx.x * 256 + threadIdx.x;
    if (idx >= KP*KP) return;
    int m = idx >> 10, k = idx & (KP-1);
    float v = 0.f;
    if (m < NN && k < NN)
        v = dinv[m] * (adj[(size_t)m*NN + k] + (m == k ? 1.f : 0.f)) * dinv[k];
    unsigned short h = f2bf(v);
    Lhi[idx] = h;
    Llo[idx] = f2bf(v - bf2f(h));
}

// ---------------- x projection -> xT[j=b*40+a][n] bf16 ----------------
__global__ __launch_bounds__(256)
void k_xproj(const float* __restrict__ inputs, int t,
             const float* __restrict__ Wo, const float* __restrict__ bo,
             const float* __restrict__ Wd, const float* __restrict__ bd,
             const float* __restrict__ We, const float* __restrict__ be,
             const float* __restrict__ Wi, const float* __restrict__ bi,
             unsigned short* __restrict__ xT) {
    int b = blockIdx.x, nt = blockIdx.y;
    int n0 = nt * 64;
    __shared__ float raw[64][22];
    for (int i = threadIdx.x; i < 64*21; i += 256) {
        int nn = i / 21, f = i - nn*21;
        int n = n0 + nn;
        raw[nn][f] = (n < NN) ? inputs[(((size_t)b*SEQ + t)*NN + n)*21 + f] : 0.f;
    }
    __syncthreads();
    for (int o = threadIdx.x; o < 40*64; o += 256) {
        int a2 = o >> 6, nn = o & 63;
        int n = n0 + nn;
        if (n >= NN) continue;
        int a = a2 % 10, g = a2 / 10;
        const float* r = raw[nn];
        float v;
        if (g == 0)
            v = bo[a] + r[2]*Wo[0*10+a] + r[5]*Wo[1*10+a] + r[8]*Wo[2*10+a]
                      + r[9]*Wo[3*10+a] + r[12]*Wo[4*10+a];
        else if (g == 1)
            v = bd[a] + r[10]*Wd[0*10+a] + r[14]*Wd[1*10+a] + r[15]*Wd[2*10+a];
        else if (g == 2)
            v = be[a] + r[13]*We[0*10+a] + r[17]*We[1*10+a];
        else
            v = bi[a] + r[19]*Wi[0*10+a] + r[20]*Wi[1*10+a];
        xT[(size_t)(b*40 + a2)*KP + n] = f2bf(v);
    }
}

// ---------------- MFMA GEMM: C[m][j] += sum_k A[m][k]*B[j][k] ----------------
// A: [1024][1024] bf16 hi/lo.  B: [ncols][1024] bf16 (hi, optional lo).
// grid (ncols/64, 8, 2) block 256. split-K via atomicAdd (C pre-zeroed).
template<int NPASS>
__global__ __launch_bounds__(256)
void k_gemm(const unsigned short* __restrict__ Ahi, const unsigned short* __restrict__ Alo,
            const unsigned short* __restrict__ Bhi, const unsigned short* __restrict__ Blo,
            float* __restrict__ C, int ncols) {
    __shared__ char sAh[128*64], sAl[128*64];   // [m][k] bf16, swizzled
    __shared__ char sBh[64*64],  sBl[64*64];    // [j][k] bf16, swizzled
    const int n0 = blockIdx.x * 64;
    const int m0 = blockIdx.y * 128;
    const int kbase = blockIdx.z * 512;
    const int tid  = threadIdx.x;
    const int wave = tid >> 6, lane = tid & 63;
    const int l15 = lane & 15, l4 = lane >> 4;

    float4v acc[2][4];
    #pragma unroll
    for (int i = 0; i < 2; ++i)
        #pragma unroll
        for (int j = 0; j < 4; ++j) acc[i][j] = (float4v){0.f,0.f,0.f,0.f};

    const int ar0 = wave*32 + l15;
    const int ar1 = ar0 + 16;
    const int aoff0 = (ar0*64 + l4*16) ^ ((ar0 & 7) << 4);
    const int aoff1 = (ar1*64 + l4*16) ^ ((ar1 & 7) << 4);
    int boff[4];
    #pragma unroll
    for (int nf = 0; nf < 4; ++nf) {
        int br = nf*16 + l15;
        boff[nf] = (br*64 + l4*16) ^ ((br & 7) << 4);
    }
    // staging maps
    const int ra0 = tid >> 2,         qa0 = tid & 3;          // A chunk tid
    const int ra1 = (tid + 256) >> 2, qa1 = (tid + 256) & 3;  // A chunk tid+256
    const int rb  = tid >> 2,         qb  = tid & 3;          // B chunk tid

    for (int kt = 0; kt < 16; ++kt) {
        int k0 = kbase + kt*32;
        __syncthreads();
        {   // stage A hi+lo: 512 16B chunks each
            size_t g0 = (size_t)(m0 + ra0)*KP + k0 + qa0*8;
            size_t g1 = (size_t)(m0 + ra1)*KP + k0 + qa1*8;
            int d0 = (ra0*64 + qa0*16) ^ ((ra0 & 7) << 4);
            int d1 = (ra1*64 + qa1*16) ^ ((ra1 & 7) << 4);
            *(uint4*)(sAh + d0) = *(const uint4*)(Ahi + g0);
            *(uint4*)(sAh + d1) = *(const uint4*)(Ahi + g1);
            *(uint4*)(sAl + d0) = *(const uint4*)(Alo + g0);
            *(uint4*)(sAl + d1) = *(const uint4*)(Alo + g1);
        }
        {   // stage B: 256 16B chunks per buffer
            size_t gb = (size_t)(n0 + rb)*KP + k0 + qb*8;
            int db = (rb*64 + qb*16) ^ ((rb & 7) << 4);
            *(uint4*)(sBh + db) = *(const uint4*)(Bhi + gb);
            if (NPASS == 3)
                *(uint4*)(sBl + db) = *(const uint4*)(Blo + gb);
        }
        __syncthreads();
        short8v a0h = *(const short8v*)(sAh + aoff0);
        short8v a1h = *(const short8v*)(sAh + aoff1);
        short8v a0l = *(const short8v*)(sAl + aoff0);
        short8v a1l = *(const short8v*)(sAl + aoff1);
        #pragma unroll
        for (int nf = 0; nf < 4; ++nf) {
            short8v bh = *(const short8v*)(sBh + boff[nf]);
            acc[0][nf] = __builtin_amdgcn_mfma_f32_16x16x32_bf16(a0h, bh, acc[0][nf], 0, 0, 0);
            acc[1][nf] = __builtin_amdgcn_mfma_f32_16x16x32_bf16(a1h, bh, acc[1][nf], 0, 0, 0);
            acc[0][nf] = __builtin_amdgcn_mfma_f32_16x16x32_bf16(a0l, bh, acc[0][nf], 0, 0, 0);
            acc[1][nf] = __builtin_amdgcn_mfma_f32_16x16x32_bf16(a1l, bh, acc[1][nf], 0, 0, 0);
            if (NPASS == 3) {
                short8v bl = *(const short8v*)(sBl + boff[nf]);
                acc[0][nf] = __builtin_amdgcn_mfma_f32_16x16x32_bf16(a0h, bl, acc[0][nf], 0, 0, 0);
                acc[1][nf] = __builtin_amdgcn_mfma_f32_16x16x32_bf16(a1h, bl, acc[1][nf], 0, 0, 0);
            }
        }
    }
    #pragma unroll
    for (int mf = 0; mf < 2; ++mf)
        #pragma unroll
        for (int nf = 0; nf < 4; ++nf)
            #pragma unroll
            for (int i = 0; i < 4; ++i) {
                int m = m0 + wave*32 + mf*16 + l4*4 + i;
                int j = n0 + nf*16 + l15;
                atomicAdd(&C[(size_t)m*ncols + j], acc[mf][nf][i]);
            }
}

// ---------------- gate: ru[b][m*128+k] = sigmoid(agrow @ W1 + b1) ----------------
__global__ __launch_bounds__(128)
void k_gate(const float* __restrict__ agx, const float* __restrict__ agh,
            const float* __restrict__ W1, const float* __restrict__ b1,
            float* __restrict__ ru) {
    int b = blockIdx.x, mt = blockIdx.y;   // (32, 40), 25 m each
    int k = threadIdx.x;
    float w[104];
    #pragma unroll
    for (int f = 0; f < 104; ++f) w[f] = W1[f*GATEW + k];
    float bias = b1[k];
    __shared__ float row[104];
    for (int mi = 0; mi < 25; ++mi) {
        int m = mt*25 + mi;
        __syncthreads();
        if (k < 40) row[k] = agx[(size_t)m*XCOLS + b*40 + k];
        if (k < 64) row[40 + k] = agh[(size_t)m*HCOLS + b*64 + k];
        __syncthreads();
        float acc = bias;
        #pragma unroll
        for (int f = 0; f < 104; ++f) acc += row[f] * w[f];
        ru[(size_t)b*128000 + m*GATEW + k] = 1.f / (1.f + __expf(-acc));
    }
}

// ---------------- rh: rhT[j=b*64+c][n] = r[b][n*64+c] * h[b][n][c] (hi/lo bf16) ----------------
__global__ __launch_bounds__(64)
void k_rh(const float* __restrict__ ru,
          const unsigned short* __restrict__ hhi, const unsigned short* __restrict__ hlo,
          unsigned short* __restrict__ rhh, unsigned short* __restrict__ rhl) {
    int b = blockIdx.x, nt = blockIdx.y;   // (32,16)
    int c = threadIdx.x;
    int n0 = nt * 64;
    __shared__ float rr[64][65];
    for (int i = c; i < 4096; i += 64) {
        int nn = i >> 6, cc = i & 63;
        int n = n0 + nn;
        rr[nn][cc] = (n < NN) ? ru[(size_t)b*128000 + n*64 + cc] : 0.f;
    }
    __syncthreads();
    size_t jrow = (size_t)(b*64 + c) * KP;
    for (int g = 0; g < 8; ++g) {
        int n = n0 + g*8;
        if (n >= NN) break;
        ushort8v vh = *(const ushort8v*)(hhi + jrow + n);
        ushort8v vl = *(const ushort8v*)(hlo + jrow + n);
        ushort8v oh, ol;
        #pragma unroll
        for (int q = 0; q < 8; ++q) {
            float h = bf2f(vh[q]) + bf2f(vl[q]);
            float x = rr[g*8 + q][c] * h;
            unsigned short xh = f2bf(x);
            oh[q] = xh;
            ol[q] = f2bf(x - bf2f(xh));
        }
        *(ushort8v*)(rhh + jrow + n) = oh;
        *(ushort8v*)(rhl + jrow + n) = ol;
    }
}

// ---------------- update ----------------
__global__ __launch_bounds__(64)
void k_update(const float* __restrict__ agx, const float* __restrict__ agc,
              const float* __restrict__ W2, const float* __restrict__ b2,
              const float* __restrict__ ru,
              const unsigned short* __restrict__ hhi, const unsigned short* __restrict__ hlo,
              unsigned short* __restrict__ nhi, unsigned short* __restrict__ nlo,
              float* __restrict__ out, int write_out) {
    int b = blockIdx.x, mt = blockIdx.y;   // (32,32), 32 m each
    int c = threadIdx.x;
    float w[104];
    #pragma unroll
    for (int f = 0; f < 104; ++f) w[f] = W2[f*HID + c];
    float bias = b2[c];
    __shared__ float row[104];
    size_t jrow = (size_t)(b*64 + c) * KP;
    for (int g = 0; g < 4; ++g) {
        int mg = mt*32 + g*8;
        if (mg >= NN) break;
        ushort8v vh = *(const ushort8v*)(hhi + jrow + mg);
        ushort8v vl = *(const ushort8v*)(hlo + jrow + mg);
        ushort8v wh, wl;
        #pragma unroll
        for (int q = 0; q < 8; ++q) {
            int m = mg + q;
            __syncthreads();
            if (c < 40) row[c] = agx[(size_t)m*XCOLS + b*40 + c];
            row[40 + c] = agc[(size_t)m*HCOLS + b*64 + c];
            __syncthreads();
            float acc = bias;
            #pragma unroll
            for (int f = 0; f < 104; ++f) acc += row[f] * w[f];
            float cv = tanhf(acc);
            float u = ru[(size_t)b*128000 + 64000 + m*64 + c];
            float h = bf2f(vh[q]) + bf2f(vl[q]);
            float hn = u*h + (1.f - u)*cv;
            unsigned short hh2 = f2bf(hn);
            wh[q] = hh2;
            wl[q] = f2bf(hn - bf2f(hh2));
            if (write_out) out[((size_t)b*NN + m)*HID + c] = hn;
        }
        *(ushort8v*)(nhi + jrow + mg) = wh;
        *(ushort8v*)(nlo + jrow + mg) = wl;
    }
}

// ---------------- workspace layout (byte offsets) ----------------
#define O_LHI   0u
#define O_LLO   2097152u
#define O_HT0H  4194304u
#define O_HT0L  8388608u
#define O_HT1H  12582912u
#define O_HT1L  16777216u
#define O_XT    20971520u
#define O_RHH   23592960u
#define O_RHL   27787264u
#define O_AGX   31981568u
#define O_AGH   37224448u
#define O_RU    45613056u
#define O_DINV  61997056u
#define WS_BYTES 62001152u

extern "C" void kernel_launch(void* const* d_in, const int* in_sizes, int n_in,
                              void* d_out, int out_size, void* d_ws, size_t ws_size,
                              hipStream_t stream) {
    const float* inputs = (const float*)d_in[0];
    const float* adj    = (const float*)d_in[1];
    const float* Wo = (const float*)d_in[2];  const float* bo = (const float*)d_in[3];
    const float* Wd = (const float*)d_in[4];  const float* bd = (const float*)d_in[5];
    const float* We = (const float*)d_in[6];  const float* be = (const float*)d_in[7];
    const float* Wi = (const float*)d_in[8];  const float* bi = (const float*)d_in[9];
    const float* W1 = (const float*)d_in[10]; const float* b1 = (const float*)d_in[11];
    const float* W2 = (const float*)d_in[12]; const float* b2 = (const float*)d_in[13];
    float* out = (float*)d_out;

    char* ws = (char*)d_ws;
    unsigned short* Lhi  = (unsigned short*)(ws + O_LHI);
    unsigned short* Llo  = (unsigned short*)(ws + O_LLO);
    unsigned short* ht0h = (unsigned short*)(ws + O_HT0H);
    unsigned short* ht0l = (unsigned short*)(ws + O_HT0L);
    unsigned short* ht1h = (unsigned short*)(ws + O_HT1H);
    unsigned short* ht1l = (unsigned short*)(ws + O_HT1L);
    unsigned short* xT   = (unsigned short*)(ws + O_XT);
    unsigned short* rhh  = (unsigned short*)(ws + O_RHH);
    unsigned short* rhl  = (unsigned short*)(ws + O_RHL);
    float* agx  = (float*)(ws + O_AGX);
    float* agh  = (float*)(ws + O_AGH);
    float* ru   = (float*)(ws + O_RU);
    float* dinv = (float*)(ws + O_DINV);

    // zero everything once (pads must be zero; h0 = 0)
    hipMemsetAsync(d_ws, 0, WS_BYTES, stream);

    k_rowsum<<<NN, 256, 0, stream>>>(adj, dinv);
    k_buildL<<<(KP*KP)/256, 256, 0, stream>>>(adj, dinv, Lhi, Llo);

    for (int t = 0; t < SEQ; ++t) {
        unsigned short* hch = (t & 1) ? ht1h : ht0h;
        unsigned short* hcl = (t & 1) ? ht1l : ht0l;
        unsigned short* hnh = (t & 1) ? ht0h : ht1h;
        unsigned short* hnl = (t & 1) ? ht0l : ht1l;

        k_xproj<<<dim3(32,16), 256, 0, stream>>>(inputs, t, Wo, bo, Wd, bd,
                                                 We, be, Wi, bi, xT);
        hipMemsetAsync(agx, 0, (size_t)(O_RU - O_AGX), stream);   // agx + agh
        k_gemm<2><<<dim3(XCOLS/64, 8, 2), 256, 0, stream>>>(Lhi, Llo, xT, (const unsigned short*)0, agx, XCOLS);
        k_gemm<3><<<dim3(HCOLS/64, 8, 2), 256, 0, stream>>>(Lhi, Llo, hch, hcl, agh, HCOLS);
        k_gate<<<dim3(32,40), 128, 0, stream>>>(agx, agh, W1, b1, ru);
        k_rh<<<dim3(32,16), 64, 0, stream>>>(ru, hch, hcl, rhh, rhl);
        hipMemsetAsync(agh, 0, (size_t)(O_RU - O_AGH), stream);
        k_gemm<3><<<dim3(HCOLS/64, 8, 2), 256, 0, stream>>>(Lhi, Llo, rhh, rhl, agh, HCOLS);
        k_update<<<dim3(32,32), 64, 0, stream>>>(agx, agh, W2, b2, ru, hch, hcl,
                                                 hnh, hnl, out, t == SEQ-1);
    }
}

// Round 3
// 6096.514 us; speedup vs baseline: 3.1700x; 1.8779x over previous
//
#include <hip/hip_runtime.h>
#include <math.h>

#define NN    1000
#define KP    1024
#define BATCH 32
#define SEQ   48
#define HID   64
#define FEAT  40
#define AGW   3328                  // 1280 x-cols + 2048 h-cols
#define HCOLS 2048

typedef unsigned short u16;
typedef __attribute__((ext_vector_type(8))) short  short8v;
typedef __attribute__((ext_vector_type(8))) unsigned short ushort8v;
typedef __attribute__((ext_vector_type(4))) float  float4v;

__device__ __forceinline__ u16 f2bf(float x) {
    union { float f; unsigned u; } v; v.f = x;
    unsigned r = v.u + 0x7FFF + ((v.u >> 16) & 1);
    return (u16)(r >> 16);
}
__device__ __forceinline__ float bf2f(u16 h) {
    union { unsigned u; float f; } v; v.u = ((unsigned)h) << 16;
    return v.f;
}

// ---------------- Laplacian ----------------
__global__ void k_rowsum(const float* __restrict__ adj, float* __restrict__ dinv) {
    int m = blockIdx.x;
    float s = 0.f;
    for (int n = threadIdx.x; n < NN; n += blockDim.x)
        s += adj[(size_t)m*NN + n];
    __shared__ float red[256];
    red[threadIdx.x] = s; __syncthreads();
    for (int st = 128; st > 0; st >>= 1) {
        if (threadIdx.x < st) red[threadIdx.x] += red[threadIdx.x + st];
        __syncthreads();
    }
    if (threadIdx.x == 0) dinv[m] = rsqrtf(red[0] + 1.0f);
}

__global__ void k_buildL(const float* __restrict__ adj, const float* __restrict__ dinv,
                         u16* __restrict__ Lhi, u16* __restrict__ Llo) {
    int idx = blockIdx.x * 256 + threadIdx.x;
    if (idx >= KP*KP) return;
    int m = idx >> 10, k = idx & (KP-1);
    float v = 0.f;
    if (m < NN && k < NN)
        v = dinv[m] * (adj[(size_t)m*NN + k] + (m == k ? 1.f : 0.f)) * dinv[k];
    u16 h = f2bf(v);
    Lhi[idx] = h;
    Llo[idx] = f2bf(v - bf2f(h));
}

// ---------------- W conversion: W1bf[k 128][f 128], W2bf[c 64][f 128] hi/lo ----------------
__global__ void k_wconv(const float* __restrict__ W1, const float* __restrict__ W2,
                        u16* __restrict__ W1h, u16* __restrict__ W1l,
                        u16* __restrict__ W2h, u16* __restrict__ W2l) {
    int idx = blockIdx.x * 256 + threadIdx.x;
    if (idx < 128*128) {
        int k = idx >> 7, f = idx & 127;
        float v = (f < 104) ? W1[f*128 + k] : 0.f;
        u16 h = f2bf(v);
        W1h[idx] = h; W1l[idx] = f2bf(v - bf2f(h));
    } else if (idx < 128*128 + 64*128) {
        int i2 = idx - 128*128;
        int c = i2 >> 7, f = i2 & 127;
        float v = (f < 104) ? W2[f*64 + c] : 0.f;
        u16 h = f2bf(v);
        W2h[i2] = h; W2l[i2] = f2bf(v - bf2f(h));
    }
}

// ---------------- x projection -> xT[j=b*40+a][n] bf16 ----------------
__global__ __launch_bounds__(256)
void k_xproj(const float* __restrict__ inputs, int t,
             const float* __restrict__ Wo, const float* __restrict__ bo,
             const float* __restrict__ Wd, const float* __restrict__ bd,
             const float* __restrict__ We, const float* __restrict__ be,
             const float* __restrict__ Wi, const float* __restrict__ bi,
             u16* __restrict__ xT) {
    int b = blockIdx.x, nt = blockIdx.y;
    int n0 = nt * 64;
    __shared__ float raw[64][22];
    for (int i = threadIdx.x; i < 64*21; i += 256) {
        int nn = i / 21, f = i - nn*21;
        int n = n0 + nn;
        raw[nn][f] = (n < NN) ? inputs[(((size_t)b*SEQ + t)*NN + n)*21 + f] : 0.f;
    }
    __syncthreads();
    for (int o = threadIdx.x; o < 40*64; o += 256) {
        int a2 = o >> 6, nn = o & 63;
        int n = n0 + nn;
        if (n >= NN) continue;
        int a = a2 % 10, g = a2 / 10;
        const float* r = raw[nn];
        float v;
        if (g == 0)
            v = bo[a] + r[2]*Wo[0*10+a] + r[5]*Wo[1*10+a] + r[8]*Wo[2*10+a]
                      + r[9]*Wo[3*10+a] + r[12]*Wo[4*10+a];
        else if (g == 1)
            v = bd[a] + r[10]*Wd[0*10+a] + r[14]*Wd[1*10+a] + r[15]*Wd[2*10+a];
        else if (g == 2)
            v = be[a] + r[13]*We[0*10+a] + r[17]*We[1*10+a];
        else
            v = bi[a] + r[19]*Wi[0*10+a] + r[20]*Wi[1*10+a];
        xT[(size_t)(b*40 + a2)*KP + n] = f2bf(v);
    }
}

// ---------------- MFMA GEMM: C[m][n0+j] = sum_k A[m][k]*B[j][k] ----------------
// 512 thr, 8 waves, BM=128 BN=64 BK=32, no split-K, direct store.
// blocks [0,xblocks): B=Bx (2-pass, no B-lo); rest: B=Bh/Bhl (3-pass).
__global__ __launch_bounds__(512)
void k_gemm(const u16* __restrict__ Ahi, const u16* __restrict__ Alo,
            const u16* __restrict__ Bx,
            const u16* __restrict__ Bh, const u16* __restrict__ Bhl,
            int xblocks, float* __restrict__ C, int ncols) {
    __shared__ char sAh[128*64], sAl[128*64];
    __shared__ char sBh[64*64],  sBl[64*64];
    const int n0 = blockIdx.x * 64;
    const int m0 = blockIdx.y * 128;
    const bool isx = (int)blockIdx.x < xblocks;
    const u16* Bp  = isx ? Bx : Bh;
    const int brow0 = isx ? n0 : n0 - xblocks*64;
    const int tid = threadIdx.x;
    const int w = tid >> 6, lane = tid & 63;
    const int l15 = lane & 15, l4 = lane >> 4;

    float4v acc[4];
    #pragma unroll
    for (int i = 0; i < 4; ++i) acc[i] = (float4v){0.f,0.f,0.f,0.f};

    const int ar = w*16 + l15;
    const int aoff = (ar*64 + l4*16) ^ ((ar & 7) << 4);
    int boff[4];
    #pragma unroll
    for (int nf = 0; nf < 4; ++nf) {
        int br = nf*16 + l15;
        boff[nf] = (br*64 + l4*16) ^ ((br & 7) << 4);
    }
    // staging maps
    const int rA = tid >> 2, qA = tid & 3;          // 512 A-chunks
    const int dA = (rA*64 + qA*16) ^ ((rA & 7) << 4);
    const size_t gA = (size_t)(m0 + rA)*KP + qA*8;
    const int rB = (tid & 255) >> 2, qB = tid & 3;  // 256 B-chunks per team
    const int dB = (rB*64 + qB*16) ^ ((rB & 7) << 4);
    const size_t gB = (size_t)(brow0 + rB)*KP + qB*8;
    const bool team0 = tid < 256;

    for (int kt = 0; kt < 32; ++kt) {
        const int k0 = kt*32;
        __syncthreads();
        *(uint4*)(sAh + dA) = *(const uint4*)(Ahi + gA + k0);
        *(uint4*)(sAl + dA) = *(const uint4*)(Alo + gA + k0);
        if (team0)      *(uint4*)(sBh + dB) = *(const uint4*)(Bp  + gB + k0);
        else if (!isx)  *(uint4*)(sBl + dB) = *(const uint4*)(Bhl + gB + k0);
        __syncthreads();
        short8v ah = *(const short8v*)(sAh + aoff);
        short8v al = *(const short8v*)(sAl + aoff);
        #pragma unroll
        for (int nf = 0; nf < 4; ++nf) {
            short8v bh = *(const short8v*)(sBh + boff[nf]);
            acc[nf] = __builtin_amdgcn_mfma_f32_16x16x32_bf16(ah, bh, acc[nf], 0, 0, 0);
            acc[nf] = __builtin_amdgcn_mfma_f32_16x16x32_bf16(al, bh, acc[nf], 0, 0, 0);
            if (!isx) {
                short8v bl = *(const short8v*)(sBl + boff[nf]);
                acc[nf] = __builtin_amdgcn_mfma_f32_16x16x32_bf16(ah, bl, acc[nf], 0, 0, 0);
            }
        }
    }
    #pragma unroll
    for (int nf = 0; nf < 4; ++nf)
        #pragma unroll
        for (int i = 0; i < 4; ++i) {
            int m = m0 + w*16 + l4*4 + i;
            int j = n0 + nf*16 + l15;
            C[(size_t)m*ncols + j] = acc[nf][i];
        }
}

// ---------------- gate (MFMA) + fused rh / u demux ----------------
// ru(m,k) = sigmoid(ag_row(m) . W1[:,k] + b1[k]); m<500 -> rh for nodes 2m,2m+1;
// m>=500 -> u for nodes 2(m-500), +1.
__global__ __launch_bounds__(256)
void k_gate(const float* __restrict__ ag, const u16* __restrict__ W1h,
            const u16* __restrict__ W1l, const float* __restrict__ b1,
            const float* __restrict__ h_lin,
            u16* __restrict__ rhh, u16* __restrict__ rhl,
            float* __restrict__ u_lin) {
    const int b = blockIdx.x, mt = blockIdx.y;   // (32,16)
    const int tid = threadIdx.x;
    const int w = tid >> 6, lane = tid & 63, l15 = lane & 15, l4 = lane >> 4;
    __shared__ char sAh[64*64], sAl[64*64];      // [64 rows][32 f] bf16/kt, swizzled
    __shared__ float ru_s[64*129];

    float4v acc[8];
    #pragma unroll
    for (int i = 0; i < 8; ++i) acc[i] = (float4v){0.f,0.f,0.f,0.f};

    const int srow = tid >> 2, sfg = tid & 3;
    const int sdst = (srow*64 + sfg*16) ^ ((srow & 7) << 4);
    const float* agrow = ag + (size_t)(mt*64 + srow)*AGW;
    const int ar = w*16 + l15;
    const int aoff = (ar*64 + l4*16) ^ ((ar & 7) << 4);

    for (int kt = 0; kt < 4; ++kt) {
        __syncthreads();
        ushort8v hv, lv;
        #pragma unroll
        for (int e = 0; e < 8; ++e) {
            int f = kt*32 + sfg*8 + e;
            float v = 0.f;
            if (f < 40)        v = agrow[b*40 + f];
            else if (f < 104)  v = agrow[1280 + b*64 + (f - 40)];
            u16 hi = f2bf(v);
            hv[e] = hi; lv[e] = f2bf(v - bf2f(hi));
        }
        *(ushort8v*)(sAh + sdst) = hv;
        *(ushort8v*)(sAl + sdst) = lv;
        __syncthreads();
        short8v ah = *(const short8v*)(sAh + aoff);
        short8v al = *(const short8v*)(sAl + aoff);
        #pragma unroll
        for (int nf = 0; nf < 8; ++nf) {
            int j = nf*16 + l15;
            short8v bh = *(const short8v*)(W1h + j*128 + kt*32 + l4*8);
            short8v bl = *(const short8v*)(W1l + j*128 + kt*32 + l4*8);
            acc[nf] = __builtin_amdgcn_mfma_f32_16x16x32_bf16(ah, bh, acc[nf], 0, 0, 0);
            acc[nf] = __builtin_amdgcn_mfma_f32_16x16x32_bf16(al, bh, acc[nf], 0, 0, 0);
            acc[nf] = __builtin_amdgcn_mfma_f32_16x16x32_bf16(ah, bl, acc[nf], 0, 0, 0);
        }
    }
    // sigmoid + dump to LDS
    #pragma unroll
    for (int nf = 0; nf < 8; ++nf) {
        int col = nf*16 + l15;
        float bias = b1[col];
        #pragma unroll
        for (int i = 0; i < 4; ++i) {
            int row = w*16 + l4*4 + i;
            float v = acc[nf][i] + bias;
            ru_s[row*129 + col] = 1.f / (1.f + __expf(-v));
        }
    }
    __syncthreads();
    // epilogue: demux r/u
    const int c = tid & 63, ng = tid >> 6;
    for (int lc = 0; lc < 16; lc += 4) {
        int lr = ng*16 + lc;
        int m = mt*64 + lr;
        if (m + 3 < 500) {          // all-r chunk (500 % 4 == 0 -> no mixed chunk)
            unsigned hiw[4], low[4];
            #pragma unroll
            for (int d = 0; d < 4; ++d) {
                int mm = m + d;
                float r0 = ru_s[(lr+d)*129 + c];
                float r1 = ru_s[(lr+d)*129 + 64 + c];
                float h0 = h_lin[((size_t)b*NN + 2*mm)*64 + c];
                float h1 = h_lin[((size_t)b*NN + 2*mm + 1)*64 + c];
                float x0 = r0*h0, x1 = r1*h1;
                u16 a0 = f2bf(x0), a1 = f2bf(x1);
                hiw[d] = (unsigned)a0 | ((unsigned)a1 << 16);
                u16 c0 = f2bf(x0 - bf2f(a0)), c1 = f2bf(x1 - bf2f(a1));
                low[d] = (unsigned)c0 | ((unsigned)c1 << 16);
            }
            size_t base = (size_t)(b*64 + c)*KP + 2*m;
            uint4 vh; vh.x = hiw[0]; vh.y = hiw[1]; vh.z = hiw[2]; vh.w = hiw[3];
            uint4 vl; vl.x = low[0]; vl.y = low[1]; vl.z = low[2]; vl.w = low[3];
            *(uint4*)(rhh + base) = vh;
            *(uint4*)(rhl + base) = vl;
        } else if (m >= 500) {      // u chunk
            #pragma unroll
            for (int d = 0; d < 4; ++d) {
                int mm = m + d;
                if (mm < 1000) {
                    int n = 2*(mm - 500);
                    u_lin[((size_t)b*NN + n)*64 + c]     = ru_s[(lr+d)*129 + c];
                    u_lin[((size_t)b*NN + n + 1)*64 + c] = ru_s[(lr+d)*129 + 64 + c];
                }
            }
        }
    }
}

// ---------------- update (MFMA) + h' + hT transpose-write ----------------
__global__ __launch_bounds__(256)
void k_update(const float* __restrict__ ag, const float* __restrict__ agc,
              const u16* __restrict__ W2h, const u16* __restrict__ W2l,
              const float* __restrict__ b2, const float* __restrict__ u_lin,
              float* __restrict__ h_lin,
              u16* __restrict__ hTh, u16* __restrict__ hTl,
              float* __restrict__ out, int write_out) {
    const int b = blockIdx.x, mt = blockIdx.y;   // (32,16)
    const int tid = threadIdx.x;
    const int w = tid >> 6, lane = tid & 63, l15 = lane & 15, l4 = lane >> 4;
    __shared__ char sAh[64*64], sAl[64*64];
    __shared__ float cs[64*65];

    float4v acc[4];
    #pragma unroll
    for (int i = 0; i < 4; ++i) acc[i] = (float4v){0.f,0.f,0.f,0.f};

    const int srow = tid >> 2, sfg = tid & 3;
    const int sdst = (srow*64 + sfg*16) ^ ((srow & 7) << 4);
    const float* agrow  = ag  + (size_t)(mt*64 + srow)*AGW;
    const float* agcrow = agc + (size_t)(mt*64 + srow)*HCOLS;
    const int ar = w*16 + l15;
    const int aoff = (ar*64 + l4*16) ^ ((ar & 7) << 4);

    for (int kt = 0; kt < 4; ++kt) {
        __syncthreads();
        ushort8v hv, lv;
        #pragma unroll
        for (int e = 0; e < 8; ++e) {
            int f = kt*32 + sfg*8 + e;
            float v = 0.f;
            if (f < 40)        v = agrow[b*40 + f];
            else if (f < 104)  v = agcrow[b*64 + (f - 40)];
            u16 hi = f2bf(v);
            hv[e] = hi; lv[e] = f2bf(v - bf2f(hi));
        }
        *(ushort8v*)(sAh + sdst) = hv;
        *(ushort8v*)(sAl + sdst) = lv;
        __syncthreads();
        short8v ah = *(const short8v*)(sAh + aoff);
        short8v al = *(const short8v*)(sAl + aoff);
        #pragma unroll
        for (int nf = 0; nf < 4; ++nf) {
            int j = nf*16 + l15;
            short8v bh = *(const short8v*)(W2h + j*128 + kt*32 + l4*8);
            short8v bl = *(const short8v*)(W2l + j*128 + kt*32 + l4*8);
            acc[nf] = __builtin_amdgcn_mfma_f32_16x16x32_bf16(ah, bh, acc[nf], 0, 0, 0);
            acc[nf] = __builtin_amdgcn_mfma_f32_16x16x32_bf16(al, bh, acc[nf], 0, 0, 0);
            acc[nf] = __builtin_amdgcn_mfma_f32_16x16x32_bf16(ah, bl, acc[nf], 0, 0, 0);
        }
    }
    #pragma unroll
    for (int nf = 0; nf < 4; ++nf) {
        int col = nf*16 + l15;
        float bias = b2[col];
        #pragma unroll
        for (int i = 0; i < 4; ++i) {
            int row = w*16 + l4*4 + i;
            cs[row*65 + col] = acc[nf][i] + bias;
        }
    }
    __syncthreads();
    const int c = tid & 63, ng = tid >> 6;
    for (int lc = 0; lc < 16; lc += 8) {
        int lr = ng*16 + lc;
        int m = mt*64 + lr;
        ushort8v hiv, lov;
        #pragma unroll
        for (int d = 0; d < 8; ++d) {
            int mm = m + d;
            float hn = 0.f;
            if (mm < NN) {
                float x = cs[(lr+d)*65 + c];
                x = fminf(fmaxf(x, -15.f), 15.f);
                float e = __expf(2.f*x);
                float cand = (e - 1.f) / (e + 1.f);
                size_t idx = ((size_t)b*NN + mm)*64 + c;
                float u = u_lin[idx], h = h_lin[idx];
                hn = u*h + (1.f - u)*cand;
                h_lin[idx] = hn;
                if (write_out) out[idx] = hn;
            }
            u16 hb = f2bf(hn);
            hiv[d] = hb; lov[d] = f2bf(hn - bf2f(hb));
        }
        size_t base = (size_t)(b*64 + c)*KP + m;
        *(ushort8v*)(hTh + base) = hiv;
        *(ushort8v*)(hTl + base) = lov;
    }
}

// ---------------- workspace layout (byte offsets) ----------------
#define O_LHI   0ull
#define O_LLO   2097152ull
#define O_HTH   4194304ull
#define O_HTL   8388608ull
#define O_XT    12582912ull
#define O_RHH   15204352ull
#define O_RHL   19398656ull
#define O_AG    23592960ull
#define O_AGC   37224448ull
#define O_U     45613056ull
#define O_HL    53805056ull
#define O_W1H   61997056ull
#define O_W1L   62029824ull
#define O_W2H   62062592ull
#define O_W2L   62078976ull
#define O_DINV  62095360ull

extern "C" void kernel_launch(void* const* d_in, const int* in_sizes, int n_in,
                              void* d_out, int out_size, void* d_ws, size_t ws_size,
                              hipStream_t stream) {
    const float* inputs = (const float*)d_in[0];
    const float* adj    = (const float*)d_in[1];
    const float* Wo = (const float*)d_in[2];  const float* bo = (const float*)d_in[3];
    const float* Wd = (const float*)d_in[4];  const float* bd = (const float*)d_in[5];
    const float* We = (const float*)d_in[6];  const float* be = (const float*)d_in[7];
    const float* Wi = (const float*)d_in[8];  const float* bi = (const float*)d_in[9];
    const float* W1 = (const float*)d_in[10]; const float* b1 = (const float*)d_in[11];
    const float* W2 = (const float*)d_in[12]; const float* b2 = (const float*)d_in[13];
    float* out = (float*)d_out;

    char* ws = (char*)d_ws;
    u16* Lhi = (u16*)(ws + O_LHI);
    u16* Llo = (u16*)(ws + O_LLO);
    u16* hTh = (u16*)(ws + O_HTH);
    u16* hTl = (u16*)(ws + O_HTL);
    u16* xT  = (u16*)(ws + O_XT);
    u16* rhh = (u16*)(ws + O_RHH);
    u16* rhl = (u16*)(ws + O_RHL);
    float* ag    = (float*)(ws + O_AG);
    float* agc   = (float*)(ws + O_AGC);
    float* u_lin = (float*)(ws + O_U);
    float* h_lin = (float*)(ws + O_HL);
    u16* W1h = (u16*)(ws + O_W1H);
    u16* W1l = (u16*)(ws + O_W1L);
    u16* W2h = (u16*)(ws + O_W2H);
    u16* W2l = (u16*)(ws + O_W2L);
    float* dinv = (float*)(ws + O_DINV);

    // h0 = 0 (hT hi+lo contiguous, h_lin)
    hipMemsetAsync(ws + O_HTH, 0, 8388608ull, stream);
    hipMemsetAsync(ws + O_HL,  0, 8192000ull, stream);

    k_rowsum<<<NN, 256, 0, stream>>>(adj, dinv);
    k_buildL<<<(KP*KP)/256, 256, 0, stream>>>(adj, dinv, Lhi, Llo);
    k_wconv<<<96, 256, 0, stream>>>(W1, W2, W1h, W1l, W2h, W2l);

    for (int t = 0; t < SEQ; ++t) {
        k_xproj<<<dim3(32,16), 256, 0, stream>>>(inputs, t, Wo, bo, Wd, bd,
                                                 We, be, Wi, bi, xT);
        // ag = L @ [x | h]
        k_gemm<<<dim3(52,8), 512, 0, stream>>>(Lhi, Llo, xT, hTh, hTl, 20, ag, AGW);
        k_gate<<<dim3(32,16), 256, 0, stream>>>(ag, W1h, W1l, b1, h_lin, rhh, rhl, u_lin);
        // agc = L @ rh
        k_gemm<<<dim3(32,8), 512, 0, stream>>>(Lhi, Llo, (const u16*)0, rhh, rhl, 0, agc, HCOLS);
        k_update<<<dim3(32,16), 256, 0, stream>>>(ag, agc, W2h, W2l, b2, u_lin, h_lin,
                                                  hTh, hTl, out, t == SEQ-1);
    }
}